// Round 8
// baseline (866.223 us; speedup 1.0000x reference)
//
#include <hip/hip_runtime.h>
#include <hip/hip_bf16.h>
#include <hip/hip_cooperative_groups.h>
#include <math.h>

#define NN 20000      // nodes
#define ER 640000     // raw edges
#define ET 660000     // edges incl. self loops
#define D1 128
#define D2 256
#define EPSV 1e-5f
#define SLOPE 0.2f
#define NT1 313       // ceil(NN/64) row tiles
#define NHIST 64      // degree histogram units
#define HCH 10000     // edges per hist unit (ER/NHIST); max count 10000 < 65536 (ushort-packed)

typedef __attribute__((ext_vector_type(8))) short bf16x8;
typedef __attribute__((ext_vector_type(4))) float f32x4;

namespace cg = cooperative_groups;

struct P {
  const float* x; const void* ei;
  const float* W1; const float* att_s1; const float* att_d1; const float* bias1;
  const float* gamma1; const float* beta1;
  const float* W2; const float* att_s2; const float* att_d2; const float* bias2;
  const float* gamma2; const float* beta2;
  __hip_bfloat16* hx1b; __hip_bfloat16* hx2b;
  float* out1; float* out2;
  float2* as1; float2* ad1; float2* as2; float2* ad2;
  float* bn;                 // 768: bns1[0..127]|bnq1[128..255]|bns2[256..511]|bnq2[512..767]
  unsigned int* dpart;       // NHIST * HCH uints (ushort-packed per node pair)
  int* begv; int* endv; int* cursor; int* gcount;
  int* srcs;
  float* dout;
  int ph_lo, ph_hi, coop;
};

// ---------- helpers ----------
__device__ __forceinline__ int detect64(const void* ei) {
  const int* p = (const int*)ei;
  return (p[1] | p[3] | p[5] | p[7]) == 0;
}
__device__ __forceinline__ int clampn(int v) { return v < 0 ? 0 : (v >= NN ? NN-1 : v); }
__device__ __forceinline__ float bf16_lo(unsigned int u){ return __uint_as_float(u<<16); }
__device__ __forceinline__ float bf16_hi(unsigned int u){ return __uint_as_float(u & 0xffff0000u); }

// ---------- phase 0 units ----------
__device__ void gemm1_tile(int u, const P& p, char* smem) {
  auto As = (__hip_bfloat16 (*)[72])smem;                 // 64 rows  (9216 B)
  auto Bs = (__hip_bfloat16 (*)[72])(smem + 9216);        // 128 rows (18432 B)
  float* asred = (float*)(smem + 27648);                  // [4][64]
  float* adred = (float*)(smem + 28672);                  // [4][64]
  int t = threadIdx.x;
  int m0 = u * 64;
  for (int i = t; i < 512; i += 256) {                    // stage x fp32->bf16
    int r = i >> 3, s = i & 7;
    int gr = m0 + r; if (gr >= NN) gr = NN - 1;
    float4 f0 = ((const float4*)(p.x + (size_t)gr*64))[s*2];
    float4 f1 = ((const float4*)(p.x + (size_t)gr*64))[s*2+1];
    __hip_bfloat16 hb[8] = {
      __float2bfloat16(f0.x), __float2bfloat16(f0.y), __float2bfloat16(f0.z), __float2bfloat16(f0.w),
      __float2bfloat16(f1.x), __float2bfloat16(f1.y), __float2bfloat16(f1.z), __float2bfloat16(f1.w)};
    *(uint4*)&As[r][s*8] = *(uint4*)hb;
  }
  for (int i = t; i < 8192; i += 256) {                   // Bs[n][k] = bf16(W1[k][n]) inline transpose
    int n = i & 127, k = i >> 7;
    Bs[n][k] = __float2bfloat16(p.W1[k*128 + n]);
  }
  __syncthreads();
  int w = t >> 6, lane = t & 63, lm = lane & 15, q = lane >> 4;
  f32x4 acc[4][2];
  #pragma unroll
  for (int rt = 0; rt < 4; rt++)
    #pragma unroll
    for (int ct = 0; ct < 2; ct++) acc[rt][ct] = (f32x4){0.f,0.f,0.f,0.f};
  #pragma unroll
  for (int kc = 0; kc < 2; kc++) {
    bf16x8 bfr[2];
    #pragma unroll
    for (int ct = 0; ct < 2; ct++)
      bfr[ct] = *(const bf16x8*)&Bs[w*32 + ct*16 + lm][kc*32 + q*8];
    #pragma unroll
    for (int rt = 0; rt < 4; rt++) {
      bf16x8 a = *(const bf16x8*)&As[rt*16 + lm][kc*32 + q*8];
      acc[rt][0] = __builtin_amdgcn_mfma_f32_16x16x32_bf16(a, bfr[0], acc[rt][0], 0, 0, 0);
      acc[rt][1] = __builtin_amdgcn_mfma_f32_16x16x32_bf16(a, bfr[1], acc[rt][1], 0, 0, 0);
    }
  }
  #pragma unroll
  for (int rt = 0; rt < 4; rt++)
    #pragma unroll
    for (int ct = 0; ct < 2; ct++)
      #pragma unroll
      for (int rg = 0; rg < 4; rg++) {
        int row = m0 + rt*16 + q*4 + rg;
        int col = w*32 + ct*16 + lm;
        if (row < NN) p.hx1b[(size_t)row*128 + col] = __float2bfloat16(acc[rt][ct][rg]);
      }
  float asc[2], adc[2];
  #pragma unroll
  for (int ct = 0; ct < 2; ct++) {
    int col = w*32 + ct*16 + lm;
    asc[ct] = p.att_s1[col]; adc[ct] = p.att_d1[col];
  }
  #pragma unroll
  for (int rt = 0; rt < 4; rt++)
    #pragma unroll
    for (int rg = 0; rg < 4; rg++) {
      float ps = acc[rt][0][rg]*asc[0] + acc[rt][1][rg]*asc[1];
      float pd = acc[rt][0][rg]*adc[0] + acc[rt][1][rg]*adc[1];
      #pragma unroll
      for (int o = 1; o < 16; o <<= 1) { ps += __shfl_xor(ps, o); pd += __shfl_xor(pd, o); }
      if (lm == 0) { int row = rt*16 + q*4 + rg; asred[w*64+row] = ps; adred[w*64+row] = pd; }
    }
  __syncthreads();
  if (t < 64) {
    int row = m0 + t;
    if (row < NN) {
      p.as1[row] = make_float2(asred[t] + asred[64+t], asred[128+t] + asred[192+t]);
      p.ad1[row] = make_float2(adred[t] + adred[64+t], adred[128+t] + adred[192+t]);
    }
  }
  __syncthreads();
}

__device__ void hist_unit(int db, const P& p, char* smem) {
  unsigned int* hist = (unsigned int*)smem;     // 10000 uints (ushort-packed, 40 KB)
  int t = threadIdx.x;
  for (int i = t; i < HCH; i += 256) hist[i] = 0;
  __syncthreads();
  int base = db * HCH;
  if (detect64(p.ei)) {
    const long long* q = (const long long*)p.ei + ER;
    for (int i = base + t; i < base + HCH; i += 256) {
      int d = clampn((int)q[i]);
      atomicAdd(&hist[d>>1], 1u << ((d&1)*16));
    }
  } else {
    const int* q = (const int*)p.ei + ER;
    for (int i = base + t; i < base + HCH; i += 256) {
      int d = clampn(q[i]);
      atomicAdd(&hist[d>>1], 1u << ((d&1)*16));
    }
  }
  __syncthreads();
  for (int i = t; i < HCH; i += 256) p.dpart[db*HCH + i] = hist[i];
  __syncthreads();
}

// ---------- phase 1: parallel segment allocator ----------
__device__ void alloc_unit(int u, const P& p, char* smem) {
  int* wsum  = (int*)smem;
  int* wbase = wsum + 4;
  int t = threadIdx.x;
  int gid = u*256 + t;
  int d = 0;
  if (gid < NN) {
    d = 1;                                        // self loop
    int half = (gid & 1) * 16;
    int idx = gid >> 1;
    for (int db = 0; db < NHIST; db++)
      d += (p.dpart[db*HCH + idx] >> half) & 0xffff;
  }
  int lane = t & 63, w = t >> 6;
  int v = d;
  #pragma unroll
  for (int o = 1; o < 64; o <<= 1) {
    int uu = __shfl_up(v, o);
    if (lane >= o) v += uu;
  }
  if (lane == 63) wsum[w] = v;
  __syncthreads();
  if (t == 0) {
    int s0 = wsum[0], s1 = wsum[1], s2 = wsum[2], s3 = wsum[3];
    int b = atomicAdd(p.gcount, s0 + s1 + s2 + s3);
    wbase[0] = b; wbase[1] = b + s0; wbase[2] = b + s0 + s1; wbase[3] = b + s0 + s1 + s2;
  }
  __syncthreads();
  if (gid < NN) {
    int beg = wbase[w] + v - d;
    p.begv[gid] = beg; p.cursor[gid] = beg; p.endv[gid] = beg + d;
  }
  __syncthreads();
}

// ---------- phase 2: scatter ----------
__device__ void scatter_phase(const P& p, int gtid, int GT) {
  int is64 = detect64(p.ei);
  for (int u = gtid; u < ET/4; u += GT) {
    int i0 = u*4;
    int s[4], d[4];
    if (i0 >= ER) {
      #pragma unroll
      for (int k = 0; k < 4; k++) { s[k] = i0 + k - ER; d[k] = s[k]; }
    } else if (is64) {
      const long long* p64 = (const long long*)p.ei;
      uint4 qa = *(const uint4*)(p64 + i0);
      uint4 qb = *(const uint4*)(p64 + i0 + 2);
      uint4 ra = *(const uint4*)(p64 + ER + i0);
      uint4 rb = *(const uint4*)(p64 + ER + i0 + 2);
      s[0]=clampn((int)qa.x); s[1]=clampn((int)qa.z); s[2]=clampn((int)qb.x); s[3]=clampn((int)qb.z);
      d[0]=clampn((int)ra.x); d[1]=clampn((int)ra.z); d[2]=clampn((int)rb.x); d[3]=clampn((int)rb.z);
    } else {
      const int* p32 = (const int*)p.ei;
      uint4 qs = *(const uint4*)(p32 + i0);
      uint4 qd = *(const uint4*)(p32 + ER + i0);
      s[0]=clampn((int)qs.x); s[1]=clampn((int)qs.y); s[2]=clampn((int)qs.z); s[3]=clampn((int)qs.w);
      d[0]=clampn((int)qd.x); d[1]=clampn((int)qd.y); d[2]=clampn((int)qd.z); d[3]=clampn((int)qd.w);
    }
    #pragma unroll
    for (int k = 0; k < 4; k++) {
      int pos = atomicAdd(&p.cursor[d[k]], 1);
      p.srcs[pos] = s[k];
    }
  }
}

// ---------- phase 3: agg1 (wave-per-node, shuffle broadcast) + fused bnstats1 ----------
__device__ void agg1_phase(const P& p, char* smem, int B) {
  float* bnacc = (float*)smem;        // 256: sums[0..127], sqs[128..255]
  int t = threadIdx.x;
  for (int i = t; i < 256; i += 256) bnacc[i] = 0.f;
  __syncthreads();
  int wid = t >> 6, lane = t & 63, h = lane >> 5;   // lane owns cols 2l,2l+1
  const unsigned int* hx = (const unsigned int*)p.hx1b;
  for (int n = blockIdx.x*4 + wid; n < NN; n += B*4) {
    float2 ad = p.ad1[n];
    int beg = p.begv[n], end = p.endv[n];
    float a0=0.f, a1=0.f, z0=0.f, z1=0.f;
    for (int cb = beg; cb < end; cb += 64) {
      int len = end - cb; if (len > 64) len = 64;
      int st = 0; float p0 = 0.f, p1 = 0.f;
      if (lane < len) {
        st = p.srcs[cb + lane];
        float2 as = p.as1[st];
        float e0 = as.x + ad.x, e1 = as.y + ad.y;
        e0 = e0 > 0.f ? e0 : SLOPE*e0;
        e1 = e1 > 0.f ? e1 : SLOPE*e1;
        p0 = __expf(e0); p1 = __expf(e1);
        z0 += p0; z1 += p1;
      }
      for (int j = 0; j < len; j++) {
        int sj = __shfl(st, j);
        float q0 = __shfl(p0, j), q1 = __shfl(p1, j);
        float pj = h ? q1 : q0;
        unsigned int uu = hx[(size_t)sj*64 + lane];
        a0 += pj*bf16_lo(uu); a1 += pj*bf16_hi(uu);
      }
    }
    #pragma unroll
    for (int o = 1; o < 64; o <<= 1) { z0 += __shfl_xor(z0, o); z1 += __shfl_xor(z1, o); }
    float inv = 1.f / (h ? z1 : z0);
    float v0 = a0*inv + p.bias1[2*lane];
    float v1 = a1*inv + p.bias1[2*lane+1];
    ((float2*)(p.out1 + (size_t)n*D1))[lane] = make_float2(v0, v1);
    atomicAdd(&bnacc[2*lane], v0);       atomicAdd(&bnacc[2*lane+1], v1);
    atomicAdd(&bnacc[128+2*lane], v0*v0); atomicAdd(&bnacc[128+2*lane+1], v1*v1);
  }
  __syncthreads();
  for (int i = t; i < 256; i += 256) atomicAdd(&p.bn[i], bnacc[i]);
}

// ---------- phase 4: gemm2 tile (BN1 affine + inline W2 cast) ----------
__device__ void gemm2_tile(int u, const P& p, char* smem) {
  auto As = (__hip_bfloat16 (*)[136])smem;                 // 17408 B
  auto Bs = (__hip_bfloat16 (*)[40])(smem + 17408);        // 20480 B
  float* AB    = (float*)(smem + 37888);                   // [2][128]
  float* asred = (float*)(smem + 38912);                   // [4][64]
  float* adred = (float*)(smem + 39936);                   // [4][64]
  int t = threadIdx.x;
  int m0 = u * 64;
  if (t < 128) {
    float mean = p.bn[t]*(1.f/NN);
    float var  = p.bn[128+t]*(1.f/NN) - mean*mean;
    float A = rsqrtf(var + EPSV)*p.gamma1[t];
    AB[t] = A; AB[128+t] = p.beta1[t] - mean*A;
  }
  __syncthreads();
  for (int i = t; i < 1024; i += 256) {
    int r = i >> 4, s = i & 15;
    int gr = m0 + r; if (gr >= NN) gr = NN - 1;
    float4 f0 = ((const float4*)(p.out1 + (size_t)gr*128))[s*2];
    float4 f1 = ((const float4*)(p.out1 + (size_t)gr*128))[s*2+1];
    int c = s*8;
    float v[8] = {f0.x,f0.y,f0.z,f0.w,f1.x,f1.y,f1.z,f1.w};
    __hip_bfloat16 hb[8];
    #pragma unroll
    for (int k = 0; k < 8; k++)
      hb[k] = __float2bfloat16(fmaxf(v[k]*AB[c+k] + AB[128+c+k], 0.f));
    *(uint4*)&As[r][s*8] = *(uint4*)hb;
  }
  int w = t >> 6, lane = t & 63, lm = lane & 15, q = lane >> 4;
  f32x4 acc[4][4];
  #pragma unroll
  for (int rt = 0; rt < 4; rt++)
    #pragma unroll
    for (int ct = 0; ct < 4; ct++) acc[rt][ct] = (f32x4){0.f,0.f,0.f,0.f};
  for (int kc = 0; kc < 4; kc++) {
    __syncthreads();
    for (int i = t; i < 8192; i += 256) {       // Bs[n][kk] = bf16(W2[kc*32+kk][n])
      int n = i & 255, kk = i >> 8;
      Bs[n][kk] = __float2bfloat16(p.W2[(kc*32 + kk)*256 + n]);
    }
    __syncthreads();
    bf16x8 bfr[4];
    #pragma unroll
    for (int ct = 0; ct < 4; ct++)
      bfr[ct] = *(const bf16x8*)&Bs[w*64 + ct*16 + lm][q*8];
    #pragma unroll
    for (int rt = 0; rt < 4; rt++) {
      bf16x8 a = *(const bf16x8*)&As[rt*16 + lm][kc*32 + q*8];
      #pragma unroll
      for (int ct = 0; ct < 4; ct++)
        acc[rt][ct] = __builtin_amdgcn_mfma_f32_16x16x32_bf16(a, bfr[ct], acc[rt][ct], 0, 0, 0);
    }
  }
  #pragma unroll
  for (int rt = 0; rt < 4; rt++)
    #pragma unroll
    for (int ct = 0; ct < 4; ct++)
      #pragma unroll
      for (int rg = 0; rg < 4; rg++) {
        int row = m0 + rt*16 + q*4 + rg;
        int col = w*64 + ct*16 + lm;
        if (row < NN) p.hx2b[(size_t)row*256 + col] = __float2bfloat16(acc[rt][ct][rg]);
      }
  float asc[4], adc[4];
  #pragma unroll
  for (int ct = 0; ct < 4; ct++) {
    int col = w*64 + ct*16 + lm;
    asc[ct] = p.att_s2[col]; adc[ct] = p.att_d2[col];
  }
  #pragma unroll
  for (int rt = 0; rt < 4; rt++)
    #pragma unroll
    for (int rg = 0; rg < 4; rg++) {
      float ps = acc[rt][0][rg]*asc[0] + acc[rt][1][rg]*asc[1]
               + acc[rt][2][rg]*asc[2] + acc[rt][3][rg]*asc[3];
      float pd = acc[rt][0][rg]*adc[0] + acc[rt][1][rg]*adc[1]
               + acc[rt][2][rg]*adc[2] + acc[rt][3][rg]*adc[3];
      #pragma unroll
      for (int o = 1; o < 16; o <<= 1) { ps += __shfl_xor(ps, o); pd += __shfl_xor(pd, o); }
      if (lm == 0) { int row = rt*16 + q*4 + rg; asred[w*64+row] = ps; adred[w*64+row] = pd; }
    }
  __syncthreads();
  if (t < 64) {
    int row = m0 + t;
    if (row < NN) {
      p.as2[row] = make_float2(asred[t] + asred[64+t], asred[128+t] + asred[192+t]);
      p.ad2[row] = make_float2(adred[t] + adred[64+t], adred[128+t] + adred[192+t]);
    }
  }
  __syncthreads();
}

// ---------- phase 5: agg2 + fused bnstats2 ----------
__device__ void agg2_phase(const P& p, char* smem, int B) {
  float* bnacc = (float*)smem;        // 512: sums[0..255], sqs[256..511]
  int t = threadIdx.x;
  for (int i = t; i < 512; i += 256) bnacc[i] = 0.f;
  __syncthreads();
  int wid = t >> 6, lane = t & 63, h = lane >> 5;   // lane owns cols 4l..4l+3
  const uint2* hx = (const uint2*)p.hx2b;
  for (int n = blockIdx.x*4 + wid; n < NN; n += B*4) {
    float2 ad = p.ad2[n];
    int beg = p.begv[n], end = p.endv[n];
    float a0=0.f,a1=0.f,a2=0.f,a3=0.f,z0=0.f,z1=0.f;
    for (int cb = beg; cb < end; cb += 64) {
      int len = end - cb; if (len > 64) len = 64;
      int st = 0; float p0 = 0.f, p1 = 0.f;
      if (lane < len) {
        st = p.srcs[cb + lane];
        float2 as = p.as2[st];
        float e0 = as.x + ad.x, e1 = as.y + ad.y;
        e0 = e0 > 0.f ? e0 : SLOPE*e0;
        e1 = e1 > 0.f ? e1 : SLOPE*e1;
        p0 = __expf(e0); p1 = __expf(e1);
        z0 += p0; z1 += p1;
      }
      for (int j = 0; j < len; j++) {
        int sj = __shfl(st, j);
        float q0 = __shfl(p0, j), q1 = __shfl(p1, j);
        float pj = h ? q1 : q0;
        uint2 uu = hx[(size_t)sj*64 + lane];
        a0 += pj*bf16_lo(uu.x); a1 += pj*bf16_hi(uu.x);
        a2 += pj*bf16_lo(uu.y); a3 += pj*bf16_hi(uu.y);
      }
    }
    #pragma unroll
    for (int o = 1; o < 64; o <<= 1) { z0 += __shfl_xor(z0, o); z1 += __shfl_xor(z1, o); }
    float inv = 1.f / (h ? z1 : z0);
    float4 b4 = ((const float4*)p.bias2)[lane];
    float4 o4 = { a0*inv + b4.x, a1*inv + b4.y, a2*inv + b4.z, a3*inv + b4.w };
    ((float4*)(p.out2 + (size_t)n*D2))[lane] = o4;
    int c = 4*lane;
    atomicAdd(&bnacc[c],   o4.x); atomicAdd(&bnacc[c+1], o4.y);
    atomicAdd(&bnacc[c+2], o4.z); atomicAdd(&bnacc[c+3], o4.w);
    atomicAdd(&bnacc[256+c],   o4.x*o4.x); atomicAdd(&bnacc[256+c+1], o4.y*o4.y);
    atomicAdd(&bnacc[256+c+2], o4.z*o4.z); atomicAdd(&bnacc[256+c+3], o4.w*o4.w);
  }
  __syncthreads();
  for (int i = t; i < 512; i += 256) atomicAdd(&p.bn[256+i], bnacc[i]);
}

// ---------- the monolith ----------
__global__ __launch_bounds__(256, 4) void k_mono(P p) {
  __shared__ __attribute__((aligned(16))) char smem[40960];
  cg::grid_group g = cg::this_grid();
  int B = gridDim.x, bid = blockIdx.x, t = threadIdx.x;
  int gtid = bid*256 + t, GT = B*256;
  for (int ph = p.ph_lo; ph < p.ph_hi; ph++) {
    switch (ph) {
      case 0:
        for (int u = bid; u < NT1 + NHIST + 1; u += B) {
          if (u < NT1) gemm1_tile(u, p, smem);
          else if (u < NT1 + NHIST) hist_unit(u - NT1, p, smem);
          else {
            if (t == 0) *p.gcount = 0;
            for (int i = t; i < 768; i += 256) p.bn[i] = 0.f;
          }
        }
        break;
      case 1:
        for (int u = bid; u < (NN + 255)/256; u += B) alloc_unit(u, p, smem);
        break;
      case 2: scatter_phase(p, gtid, GT); break;
      case 3: agg1_phase(p, smem, B); break;
      case 4:
        for (int u = bid; u < NT1; u += B) gemm2_tile(u, p, smem);
        break;
      case 5: agg2_phase(p, smem, B); break;
      case 6:
        for (int i = gtid; i < NN*64; i += GT) {
          int c = (i & 63)*4;
          float4 v = ((const float4*)p.out2)[i];
          float r[4] = {v.x, v.y, v.z, v.w};
          #pragma unroll
          for (int k = 0; k < 4; k++) {
            float mean = p.bn[256+c+k]*(1.f/NN);
            float var  = p.bn[512+c+k]*(1.f/NN) - mean*mean;
            float o = (r[k] - mean)*rsqrtf(var + EPSV)*p.gamma2[c+k] + p.beta2[c+k];
            r[k] = o > 0.f ? o : 0.f;
          }
          float4 o4 = {r[0], r[1], r[2], r[3]};
          ((float4*)p.dout)[i] = o4;
        }
        break;
    }
    if (p.coop && ph + 1 < p.ph_hi) g.sync();
  }
}

// ---------- launcher ----------
extern "C" void kernel_launch(void* const* d_in, const int* in_sizes, int n_in,
                              void* d_out, int out_size, void* d_ws, size_t ws_size,
                              hipStream_t stream) {
  P prm;
  prm.x      = (const float*)d_in[0];
  prm.ei     = d_in[1];
  prm.W1     = (const float*)d_in[2];
  prm.att_s1 = (const float*)d_in[3];
  prm.att_d1 = (const float*)d_in[4];
  prm.bias1  = (const float*)d_in[5];
  prm.gamma1 = (const float*)d_in[6];
  prm.beta1  = (const float*)d_in[7];
  prm.W2     = (const float*)d_in[8];
  prm.att_s2 = (const float*)d_in[9];
  prm.att_d2 = (const float*)d_in[10];
  prm.bias2  = (const float*)d_in[11];
  prm.gamma2 = (const float*)d_in[12];
  prm.beta2  = (const float*)d_in[13];

  char* p = (char*)d_ws;
  prm.hx1b = (__hip_bfloat16*)p; p += (size_t)NN*D1*2;
  prm.hx2b = (__hip_bfloat16*)p; p += (size_t)NN*D2*2;
  prm.out1 = (float*)p; p += (size_t)NN*D1*4;
  prm.out2 = (float*)p; p += (size_t)NN*D2*4;
  prm.as1  = (float2*)p; p += (size_t)NN*8;
  prm.ad1  = (float2*)p; p += (size_t)NN*8;
  prm.as2  = (float2*)p; p += (size_t)NN*8;
  prm.ad2  = (float2*)p; p += (size_t)NN*8;
  prm.bn   = (float*)p; p += 768*4;
  prm.dpart = (unsigned int*)p; p += (size_t)NHIST*HCH*4;
  prm.begv   = (int*)p; p += NN*4;
  prm.endv   = (int*)p; p += NN*4;
  prm.cursor = (int*)p; p += NN*4;
  prm.gcount = (int*)p; p += 16*4;
  prm.srcs   = (int*)p; p += (size_t)ET*4;
  prm.dout = (float*)d_out;

  int dev = 0; hipGetDevice(&dev);
  int ncu = 0;
  hipDeviceGetAttribute(&ncu, hipDeviceAttributeMultiprocessorCount, dev);
  if (ncu <= 0) ncu = 256;
  int coopSup = 0;
  hipDeviceGetAttribute(&coopSup, hipDeviceAttributeCooperativeLaunch, dev);
  int nb = 0;
  if (hipOccupancyMaxActiveBlocksPerMultiprocessor(&nb, k_mono, 256, 0) != hipSuccess || nb < 1)
    nb = 1;
  if (nb > 4) nb = 4;
  int grid = nb * ncu;

  if (coopSup) {
    prm.ph_lo = 0; prm.ph_hi = 7; prm.coop = 1;
    void* args[] = { (void*)&prm };
    hipLaunchCooperativeKernel(k_mono, dim3(grid), dim3(256), args, 0, stream);
  } else {
    for (int ph = 0; ph < 7; ph++) {
      prm.ph_lo = ph; prm.ph_hi = ph + 1; prm.coop = 0;
      k_mono<<<grid, 256, 0, stream>>>(prm);
    }
  }
}

// Round 9
// 260.389 us; speedup vs baseline: 3.3266x; 3.3266x over previous
//
#include <hip/hip_runtime.h>
#include <hip/hip_bf16.h>
#include <math.h>

#define NN 20000      // nodes
#define ER 640000     // raw edges
#define ET 660000     // edges incl. self loops
#define D1 128
#define D2 256
#define EPSV 1e-5f
#define SLOPE 0.2f
#define NT1 313       // ceil(NN/64) gemm1 row tiles

typedef __attribute__((ext_vector_type(8))) short bf16x8;
typedef __attribute__((ext_vector_type(4))) float f32x4;

// ---------- helpers ----------
__device__ __forceinline__ int detect64(const void* ei) {
  const int* p = (const int*)ei;
  return (p[1] | p[3] | p[5] | p[7]) == 0;
}
__device__ __forceinline__ int clampn(int v) { return v < 0 ? 0 : (v >= NN ? NN-1 : v); }
__device__ __forceinline__ float bf16_lo(unsigned int u){ return __uint_as_float(u<<16); }
__device__ __forceinline__ float bf16_hi(unsigned int u){ return __uint_as_float(u & 0xffff0000u); }

// ---------- front: W cast prep (blocks 0..159) + LDS-private degree (160..167) ----------
__global__ void k_front(const void* ei, const float* W1, const float* W2,
                        __hip_bfloat16* W1t, __hip_bfloat16* W2c, int* dpart, int* gcount) {
  extern __shared__ int hist[];
  int b = blockIdx.x, t = threadIdx.x;
  if (b == 0 && t == 0) *gcount = 0;
  if (b < 160) {
    int i = b*256 + t;
    if (i < 8192) {             // W1t[n][k]: [128][64]
      int n = i >> 6, k = i & 63;
      W1t[i] = __float2bfloat16(W1[k*128 + n]);
    } else {                    // W2c[kc][n][kk]: [4][256][32]
      int i2 = i - 8192;
      int kc = i2 >> 13, n = (i2 >> 5) & 255, kk = i2 & 31;
      W2c[i2] = __float2bfloat16(W2[(kc*32 + kk)*256 + n]);
    }
    return;
  }
  int db = b - 160;
  for (int i = t; i < NN; i += 256) hist[i] = 0;
  __syncthreads();
  int is64 = detect64(ei);
  int base = db * 80000;
  if (is64) {
    const long long* p64 = (const long long*)ei;
    for (int i = base + t*4; i < base + 80000; i += 1024) {
      uint4 qa = *(const uint4*)(p64 + ER + i);
      uint4 qb = *(const uint4*)(p64 + ER + i + 2);
      atomicAdd(&hist[clampn((int)qa.x)], 1);
      atomicAdd(&hist[clampn((int)qa.z)], 1);
      atomicAdd(&hist[clampn((int)qb.x)], 1);
      atomicAdd(&hist[clampn((int)qb.z)], 1);
    }
  } else {
    const int* p32 = (const int*)ei;
    for (int i = base + t*4; i < base + 80000; i += 1024) {
      uint4 q = *(const uint4*)(p32 + ER + i);
      atomicAdd(&hist[clampn((int)q.x)], 1);
      atomicAdd(&hist[clampn((int)q.y)], 1);
      atomicAdd(&hist[clampn((int)q.z)], 1);
      atomicAdd(&hist[clampn((int)q.w)], 1);
    }
  }
  __syncthreads();
  for (int i = t; i < NN; i += 256) dpart[db*NN + i] = hist[i];
}

// ---------- parallel segment allocator ----------
__global__ __launch_bounds__(256) void k_alloc(const int* dpart, int* begv, int* endv,
                                               int* cursor, int* gcount, float* bnz) {
  __shared__ int wsum[4], wbase[4];
  int gid = blockIdx.x*256 + threadIdx.x;
  if (gid < 768) bnz[gid] = 0.f;            // bns1|bnq1|bns2|bnq2
  int d = 0;
  if (gid < NN) {
    d = 1;                                   // self loop
    #pragma unroll
    for (int bb = 0; bb < 8; bb++) d += dpart[bb*NN + gid];
  }
  int lane = threadIdx.x & 63, w = threadIdx.x >> 6;
  int v = d;
  #pragma unroll
  for (int o = 1; o < 64; o <<= 1) {
    int u = __shfl_up(v, o);
    if (lane >= o) v += u;
  }
  if (lane == 63) wsum[w] = v;
  __syncthreads();
  if (threadIdx.x == 0) {
    int s0 = wsum[0], s1 = wsum[1], s2 = wsum[2], s3 = wsum[3];
    int b = atomicAdd(gcount, s0 + s1 + s2 + s3);
    wbase[0] = b; wbase[1] = b + s0; wbase[2] = b + s0 + s1; wbase[3] = b + s0 + s1 + s2;
  }
  __syncthreads();
  if (gid < NN) {
    int beg = wbase[w] + v - d;
    begv[gid] = beg; cursor[gid] = beg; endv[gid] = beg + d;
  }
}

// ---------- merged: gemm1 tiles (blocks 0..312) + scatter (blocks 313..957) ----------
__global__ __launch_bounds__(256) void k_gs(const float* x, const __hip_bfloat16* W1t,
                                            const float* att_s1, const float* att_d1,
                                            __hip_bfloat16* hxb, float2* as1, float2* ad1,
                                            const void* ei, int* cursor, int* srcs) {
  __shared__ __hip_bfloat16 As[64][72];
  __shared__ __hip_bfloat16 Bs[128][72];
  __shared__ float asred[4][64], adred[4][64];
  int b = blockIdx.x, t = threadIdx.x;
  if (b >= NT1) {
    // ------- scatter role -------
    int i0 = ((b - NT1)*256 + t)*4;
    if (i0 >= ET) return;
    int s[4], d[4];
    if (i0 >= ER) {
      #pragma unroll
      for (int k = 0; k < 4; k++) { s[k] = i0 + k - ER; d[k] = s[k]; }
    } else if (detect64(ei)) {
      const long long* p64 = (const long long*)ei;
      uint4 qa = *(const uint4*)(p64 + i0);
      uint4 qb = *(const uint4*)(p64 + i0 + 2);
      uint4 ra = *(const uint4*)(p64 + ER + i0);
      uint4 rb = *(const uint4*)(p64 + ER + i0 + 2);
      s[0]=clampn((int)qa.x); s[1]=clampn((int)qa.z); s[2]=clampn((int)qb.x); s[3]=clampn((int)qb.z);
      d[0]=clampn((int)ra.x); d[1]=clampn((int)ra.z); d[2]=clampn((int)rb.x); d[3]=clampn((int)rb.z);
    } else {
      const int* p32 = (const int*)ei;
      uint4 qs = *(const uint4*)(p32 + i0);
      uint4 qd = *(const uint4*)(p32 + ER + i0);
      s[0]=clampn((int)qs.x); s[1]=clampn((int)qs.y); s[2]=clampn((int)qs.z); s[3]=clampn((int)qs.w);
      d[0]=clampn((int)qd.x); d[1]=clampn((int)qd.y); d[2]=clampn((int)qd.z); d[3]=clampn((int)qd.w);
    }
    #pragma unroll
    for (int k = 0; k < 4; k++) {
      int pos = atomicAdd(&cursor[d[k]], 1);
      srcs[pos] = s[k];
    }
    return;
  }
  // ------- gemm1 role -------
  int m0 = b * 64;
  for (int i = t; i < 512; i += 256) {       // stage x fp32->bf16
    int r = i >> 3, s = i & 7;
    int gr = m0 + r; if (gr >= NN) gr = NN - 1;
    float4 f0 = ((const float4*)(x + (size_t)gr*64))[s*2];
    float4 f1 = ((const float4*)(x + (size_t)gr*64))[s*2+1];
    __hip_bfloat16 hb[8] = {
      __float2bfloat16(f0.x), __float2bfloat16(f0.y), __float2bfloat16(f0.z), __float2bfloat16(f0.w),
      __float2bfloat16(f1.x), __float2bfloat16(f1.y), __float2bfloat16(f1.z), __float2bfloat16(f1.w)};
    *(uint4*)&As[r][s*8] = *(uint4*)hb;
  }
  for (int i = t; i < 1024; i += 256) {      // Bs: W1t 128x64
    int r = i >> 3, s = i & 7;
    *(uint4*)&Bs[r][s*8] = ((const uint4*)(W1t + (size_t)r*64))[s];
  }
  __syncthreads();
  int w = t >> 6, lane = t & 63, lm = lane & 15, q = lane >> 4;
  f32x4 acc[4][2];
  #pragma unroll
  for (int rt = 0; rt < 4; rt++)
    #pragma unroll
    for (int ct = 0; ct < 2; ct++) acc[rt][ct] = (f32x4){0.f,0.f,0.f,0.f};
  #pragma unroll
  for (int kc = 0; kc < 2; kc++) {
    bf16x8 bfr[2];
    #pragma unroll
    for (int ct = 0; ct < 2; ct++)
      bfr[ct] = *(const bf16x8*)&Bs[w*32 + ct*16 + lm][kc*32 + q*8];
    #pragma unroll
    for (int rt = 0; rt < 4; rt++) {
      bf16x8 a = *(const bf16x8*)&As[rt*16 + lm][kc*32 + q*8];
      acc[rt][0] = __builtin_amdgcn_mfma_f32_16x16x32_bf16(a, bfr[0], acc[rt][0], 0, 0, 0);
      acc[rt][1] = __builtin_amdgcn_mfma_f32_16x16x32_bf16(a, bfr[1], acc[rt][1], 0, 0, 0);
    }
  }
  #pragma unroll
  for (int rt = 0; rt < 4; rt++)
    #pragma unroll
    for (int ct = 0; ct < 2; ct++)
      #pragma unroll
      for (int rg = 0; rg < 4; rg++) {
        int row = m0 + rt*16 + q*4 + rg;
        int col = w*32 + ct*16 + lm;
        if (row < NN) hxb[(size_t)row*128 + col] = __float2bfloat16(acc[rt][ct][rg]);
      }
  float asc[2], adc[2];
  #pragma unroll
  for (int ct = 0; ct < 2; ct++) {
    int col = w*32 + ct*16 + lm;
    asc[ct] = att_s1[col]; adc[ct] = att_d1[col];
  }
  #pragma unroll
  for (int rt = 0; rt < 4; rt++)
    #pragma unroll
    for (int rg = 0; rg < 4; rg++) {
      float ps = acc[rt][0][rg]*asc[0] + acc[rt][1][rg]*asc[1];
      float pd = acc[rt][0][rg]*adc[0] + acc[rt][1][rg]*adc[1];
      #pragma unroll
      for (int o = 1; o < 16; o <<= 1) { ps += __shfl_xor(ps, o); pd += __shfl_xor(pd, o); }
      if (lm == 0) { int row = rt*16 + q*4 + rg; asred[w][row] = ps; adred[w][row] = pd; }
    }
  __syncthreads();
  if (t < 64) {
    int row = m0 + t;
    if (row < NN) {
      as1[row] = make_float2(asred[0][t] + asred[1][t], asred[2][t] + asred[3][t]);
      ad1[row] = make_float2(adred[0][t] + adred[1][t], adred[2][t] + adred[3][t]);
    }
  }
}

// ---------- MFMA GEMM2 fused: out1 -> BN1+ReLU+cast -> @W2 -> hx2b + att2 scalars ----------
__global__ __launch_bounds__(256) void k_gemm2f(const float* out1, const __hip_bfloat16* W2c,
                                                const float* bns1, const float* bnq1,
                                                const float* gamma1, const float* beta1,
                                                const float* att_s2, const float* att_d2,
                                                __hip_bfloat16* hxb, float2* as2, float2* ad2) {
  __shared__ __hip_bfloat16 As[64][136];
  __shared__ __hip_bfloat16 Bs[256][40];
  __shared__ float AB[2][128];
  __shared__ float asred[4][64], adred[4][64];
  int t = threadIdx.x;
  int m0 = blockIdx.x * 64;
  if (t < 128) {
    float mean = bns1[t]*(1.f/NN);
    float var  = bnq1[t]*(1.f/NN) - mean*mean;
    float A = rsqrtf(var + EPSV)*gamma1[t];
    AB[0][t] = A; AB[1][t] = beta1[t] - mean*A;
  }
  __syncthreads();
  for (int i = t; i < 1024; i += 256) {
    int r = i >> 4, s = i & 15;
    int gr = m0 + r; if (gr >= NN) gr = NN - 1;
    float4 f0 = ((const float4*)(out1 + (size_t)gr*128))[s*2];
    float4 f1 = ((const float4*)(out1 + (size_t)gr*128))[s*2+1];
    int c = s*8;
    float v[8] = {f0.x,f0.y,f0.z,f0.w,f1.x,f1.y,f1.z,f1.w};
    __hip_bfloat16 hb[8];
    #pragma unroll
    for (int k = 0; k < 8; k++)
      hb[k] = __float2bfloat16(fmaxf(v[k]*AB[0][c+k] + AB[1][c+k], 0.f));
    *(uint4*)&As[r][s*8] = *(uint4*)hb;
  }
  int w = t >> 6, lane = t & 63, lm = lane & 15, q = lane >> 4;
  f32x4 acc[4][4];
  #pragma unroll
  for (int rt = 0; rt < 4; rt++)
    #pragma unroll
    for (int ct = 0; ct < 4; ct++) acc[rt][ct] = (f32x4){0.f,0.f,0.f,0.f};
  for (int kc = 0; kc < 4; kc++) {
    __syncthreads();
    for (int i = t; i < 1024; i += 256) {
      int r = i >> 2, s = i & 3;
      *(uint4*)&Bs[r][s*8] = ((const uint4*)(W2c + ((size_t)kc*256 + r)*32))[s];
    }
    __syncthreads();
    bf16x8 bfr[4];
    #pragma unroll
    for (int ct = 0; ct < 4; ct++)
      bfr[ct] = *(const bf16x8*)&Bs[w*64 + ct*16 + lm][q*8];
    #pragma unroll
    for (int rt = 0; rt < 4; rt++) {
      bf16x8 a = *(const bf16x8*)&As[rt*16 + lm][kc*32 + q*8];
      #pragma unroll
      for (int ct = 0; ct < 4; ct++)
        acc[rt][ct] = __builtin_amdgcn_mfma_f32_16x16x32_bf16(a, bfr[ct], acc[rt][ct], 0, 0, 0);
    }
  }
  #pragma unroll
  for (int rt = 0; rt < 4; rt++)
    #pragma unroll
    for (int ct = 0; ct < 4; ct++)
      #pragma unroll
      for (int rg = 0; rg < 4; rg++) {
        int row = m0 + rt*16 + q*4 + rg;
        int col = w*64 + ct*16 + lm;
        if (row < NN) hxb[(size_t)row*256 + col] = __float2bfloat16(acc[rt][ct][rg]);
      }
  float asc[4], adc[4];
  #pragma unroll
  for (int ct = 0; ct < 4; ct++) {
    int col = w*64 + ct*16 + lm;
    asc[ct] = att_s2[col]; adc[ct] = att_d2[col];
  }
  #pragma unroll
  for (int rt = 0; rt < 4; rt++)
    #pragma unroll
    for (int rg = 0; rg < 4; rg++) {
      float ps = acc[rt][0][rg]*asc[0] + acc[rt][1][rg]*asc[1]
               + acc[rt][2][rg]*asc[2] + acc[rt][3][rg]*asc[3];
      float pd = acc[rt][0][rg]*adc[0] + acc[rt][1][rg]*adc[1]
               + acc[rt][2][rg]*adc[2] + acc[rt][3][rg]*adc[3];
      #pragma unroll
      for (int o = 1; o < 16; o <<= 1) { ps += __shfl_xor(ps, o); pd += __shfl_xor(pd, o); }
      if (lm == 0) { int row = rt*16 + q*4 + rg; asred[w][row] = ps; adred[w][row] = pd; }
    }
  __syncthreads();
  if (t < 64) {
    int row = m0 + t;
    if (row < NN) {
      as2[row] = make_float2(asred[0][t] + asred[1][t], asred[2][t] + asred[3][t]);
      ad2[row] = make_float2(adred[0][t] + adred[1][t], adred[2][t] + adred[3][t]);
    }
  }
}

// ---------- agg layer1: 64 threads; 16 lanes/edge x uint4, 4 edge slots ----------
__global__ __launch_bounds__(64) void k_agg1(const int* begv, const int* endv, const int* srcs,
                                             const float2* asv, const float2* adv,
                                             const uint4* hx, const float* bias, float* out) {
  __shared__ float2 sp[2][64];
  int n = blockIdx.x, t = threadIdx.x;
  int el = t >> 4, c = t & 15;    // edge slot, column group (cols 8c..8c+7)
  int h = c >> 3;                  // head = 8c/64
  float2 ad = adv[n];
  int beg = begv[n], end = endv[n];
  float a[8] = {0.f,0.f,0.f,0.f,0.f,0.f,0.f,0.f};
  float z0 = 0.f, z1 = 0.f;
  for (int cb = beg; cb < end; cb += 64) {
    int len = end - cb; if (len > 64) len = 64;
    if (t < len) {
      int s = srcs[cb + t];
      float2 as = asv[s];
      float e0 = as.x + ad.x, e1 = as.y + ad.y;
      e0 = e0 > 0.f ? e0 : SLOPE*e0;
      e1 = e1 > 0.f ? e1 : SLOPE*e1;
      float p0 = __expf(e0), p1 = __expf(e1);
      sp[0][t] = make_float2(__int_as_float(s), p0);
      sp[1][t] = make_float2(__int_as_float(s), p1);
      z0 += p0; z1 += p1;
    }
    __syncthreads();
    for (int j = 0; j < len; j += 4) {
      int e = j + el;
      if (e < len) {
        float2 v = sp[h][e];
        uint4 u = hx[(size_t)__float_as_int(v.x)*16 + c];
        float pj = v.y;
        a[0] += pj*bf16_lo(u.x); a[1] += pj*bf16_hi(u.x);
        a[2] += pj*bf16_lo(u.y); a[3] += pj*bf16_hi(u.y);
        a[4] += pj*bf16_lo(u.z); a[5] += pj*bf16_hi(u.z);
        a[6] += pj*bf16_lo(u.w); a[7] += pj*bf16_hi(u.w);
      }
    }
    __syncthreads();
  }
  #pragma unroll
  for (int k = 0; k < 8; k++) {
    a[k] += __shfl_down(a[k], 32);
    a[k] += __shfl_down(a[k], 16);
  }
  #pragma unroll
  for (int o = 1; o < 64; o <<= 1) { z0 += __shfl_xor(z0, o); z1 += __shfl_xor(z1, o); }
  if (t < 16) {
    float inv = 1.f / (h ? z1 : z0);
    float4 b0 = ((const float4*)bias)[2*c];
    float4 b1 = ((const float4*)bias)[2*c+1];
    float4 o0 = { a[0]*inv + b0.x, a[1]*inv + b0.y, a[2]*inv + b0.z, a[3]*inv + b0.w };
    float4 o1 = { a[4]*inv + b1.x, a[5]*inv + b1.y, a[6]*inv + b1.z, a[7]*inv + b1.w };
    ((float4*)(out + (size_t)n*D1))[2*c]   = o0;
    ((float4*)(out + (size_t)n*D1))[2*c+1] = o1;
  }
}

// ---------- agg layer2: 64 threads; 32 lanes/edge x uint4, 2 edge slots ----------
__global__ __launch_bounds__(64) void k_agg2(const int* begv, const int* endv, const int* srcs,
                                             const float2* asv, const float2* adv,
                                             const uint4* hx, const float* bias, float* out) {
  __shared__ float2 sp[2][64];
  int n = blockIdx.x, t = threadIdx.x;
  int el = t >> 5, c = t & 31;    // edge slot, column group (cols 8c..8c+7)
  int h = c >> 4;                  // head = 8c/128
  float2 ad = adv[n];
  int beg = begv[n], end = endv[n];
  float a[8] = {0.f,0.f,0.f,0.f,0.f,0.f,0.f,0.f};
  float z0 = 0.f, z1 = 0.f;
  for (int cb = beg; cb < end; cb += 64) {
    int len = end - cb; if (len > 64) len = 64;
    if (t < len) {
      int s = srcs[cb + t];
      float2 as = asv[s];
      float e0 = as.x + ad.x, e1 = as.y + ad.y;
      e0 = e0 > 0.f ? e0 : SLOPE*e0;
      e1 = e1 > 0.f ? e1 : SLOPE*e1;
      float p0 = __expf(e0), p1 = __expf(e1);
      sp[0][t] = make_float2(__int_as_float(s), p0);
      sp[1][t] = make_float2(__int_as_float(s), p1);
      z0 += p0; z1 += p1;
    }
    __syncthreads();
    for (int j = 0; j < len; j += 2) {
      int e = j + el;
      if (e < len) {
        float2 v = sp[h][e];
        uint4 u = hx[(size_t)__float_as_int(v.x)*32 + c];
        float pj = v.y;
        a[0] += pj*bf16_lo(u.x); a[1] += pj*bf16_hi(u.x);
        a[2] += pj*bf16_lo(u.y); a[3] += pj*bf16_hi(u.y);
        a[4] += pj*bf16_lo(u.z); a[5] += pj*bf16_hi(u.z);
        a[6] += pj*bf16_lo(u.w); a[7] += pj*bf16_hi(u.w);
      }
    }
    __syncthreads();
  }
  #pragma unroll
  for (int k = 0; k < 8; k++) a[k] += __shfl_down(a[k], 32);
  #pragma unroll
  for (int o = 1; o < 64; o <<= 1) { z0 += __shfl_xor(z0, o); z1 += __shfl_xor(z1, o); }
  if (t < 32) {
    float inv = 1.f / (h ? z1 : z0);
    float4 b0 = ((const float4*)bias)[2*c];
    float4 b1 = ((const float4*)bias)[2*c+1];
    float4 o0 = { a[0]*inv + b0.x, a[1]*inv + b0.y, a[2]*inv + b0.z, a[3]*inv + b0.w };
    float4 o1 = { a[4]*inv + b1.x, a[5]*inv + b1.y, a[6]*inv + b1.z, a[7]*inv + b1.w };
    ((float4*)(out + (size_t)n*D2))[2*c]   = o0;
    ((float4*)(out + (size_t)n*D2))[2*c+1] = o1;
  }
}

// ---------- batchnorm stats ----------
template<int D>
__global__ void k_bnstats(const float* x, float* bnsum, float* bnsq) {
  const int ROWS = 100;
  int c = threadIdx.x;
  int r0 = blockIdx.x * ROWS;
  float s = 0.f, s2 = 0.f;
  for (int r = 0; r < ROWS; r++) {
    float v = x[(size_t)(r0 + r)*D + c];
    s += v; s2 += v*v;
  }
  atomicAdd(&bnsum[c], s);
  atomicAdd(&bnsq[c], s2);
}

// ---------- BN2 apply + ReLU -> fp32 d_out (float4) ----------
__global__ void k_bnapply2(const float* x, const float* bnsum, const float* bnsq,
                           const float* gamma, const float* beta, float* out) {
  int i = blockIdx.x*blockDim.x + threadIdx.x;     // float4 index
  if (i >= NN*D2/4) return;
  int c = (i & 63) * 4;
  float4 v = ((const float4*)x)[i];
  float r[4] = {v.x, v.y, v.z, v.w};
  #pragma unroll
  for (int k = 0; k < 4; k++) {
    float mean = bnsum[c+k] * (1.f/NN);
    float var  = bnsq[c+k] * (1.f/NN) - mean*mean;
    float o = (r[k] - mean) * rsqrtf(var + EPSV) * gamma[c+k] + beta[c+k];
    r[k] = o > 0.f ? o : 0.f;
  }
  float4 o4 = {r[0], r[1], r[2], r[3]};
  ((float4*)out)[i] = o4;
}

// ---------- launcher ----------
extern "C" void kernel_launch(void* const* d_in, const int* in_sizes, int n_in,
                              void* d_out, int out_size, void* d_ws, size_t ws_size,
                              hipStream_t stream) {
  const float* x      = (const float*)d_in[0];
  const void*  ei     = d_in[1];
  const float* W1     = (const float*)d_in[2];
  const float* att_s1 = (const float*)d_in[3];
  const float* att_d1 = (const float*)d_in[4];
  const float* bias1  = (const float*)d_in[5];
  const float* gamma1 = (const float*)d_in[6];
  const float* beta1  = (const float*)d_in[7];
  const float* W2     = (const float*)d_in[8];
  const float* att_s2 = (const float*)d_in[9];
  const float* att_d2 = (const float*)d_in[10];
  const float* bias2  = (const float*)d_in[11];
  const float* gamma2 = (const float*)d_in[12];
  const float* beta2  = (const float*)d_in[13];

  char* p = (char*)d_ws;
  __hip_bfloat16* hx1b = (__hip_bfloat16*)p; p += (size_t)NN*D1*2;
  __hip_bfloat16* hx2b = (__hip_bfloat16*)p; p += (size_t)NN*D2*2;
  __hip_bfloat16* W1t  = (__hip_bfloat16*)p; p += 8192*2;
  __hip_bfloat16* W2c  = (__hip_bfloat16*)p; p += 32768*2;
  float* out1 = (float*)p; p += (size_t)NN*D1*4;
  float* out2 = (float*)p; p += (size_t)NN*D2*4;
  float2* as1 = (float2*)p; p += (size_t)NN*8;
  float2* ad1 = (float2*)p; p += (size_t)NN*8;
  float2* as2 = (float2*)p; p += (size_t)NN*8;
  float2* ad2 = (float2*)p; p += (size_t)NN*8;
  float* bns1 = (float*)p; p += D1*4;     // contiguous zero region (768 floats)
  float* bnq1 = (float*)p; p += D1*4;
  float* bns2 = (float*)p; p += D2*4;
  float* bnq2 = (float*)p; p += D2*4;
  int* dpart  = (int*)p; p += (size_t)8*NN*4;
  int* begv   = (int*)p; p += NN*4;
  int* endv   = (int*)p; p += NN*4;
  int* cursor = (int*)p; p += NN*4;
  int* gcount = (int*)p; p += 16*4;
  int* srcs   = (int*)p; p += (size_t)ET*4;

  const int SCB = (ET/4 + 255)/256;        // scatter blocks
  k_front<<<168, 256, NN*sizeof(int), stream>>>(ei, W1, W2, W1t, W2c, dpart, gcount);
  k_alloc<<<(NN+255)/256, 256, 0, stream>>>(dpart, begv, endv, cursor, gcount, bns1);
  k_gs<<<NT1 + SCB, 256, 0, stream>>>(x, W1t, att_s1, att_d1, hx1b, as1, ad1,
                                      ei, cursor, srcs);

  k_agg1<<<NN, 64, 0, stream>>>(begv, endv, srcs, as1, ad1, (const uint4*)hx1b, bias1, out1);
  k_bnstats<D1><<<200, D1, 0, stream>>>(out1, bns1, bnq1);

  k_gemm2f<<<(NN+63)/64, 256, 0, stream>>>(out1, W2c, bns1, bnq1, gamma1, beta1,
                                           att_s2, att_d2, hx2b, as2, ad2);
  k_agg2<<<NN, 64, 0, stream>>>(begv, endv, srcs, as2, ad2, (const uint4*)hx2b, bias2, out2);
  k_bnstats<D2><<<200, D2, 0, stream>>>(out2, bns2, bnq2);
  k_bnapply2<<<(NN*D2/4 + 255)/256, 256, 0, stream>>>(out2, bns2, bnq2, gamma2, beta2,
                                                      (float*)d_out);
}

// Round 10
// 254.311 us; speedup vs baseline: 3.4062x; 1.0239x over previous
//
#include <hip/hip_runtime.h>
#include <hip/hip_bf16.h>
#include <math.h>

#define NN 20000      // nodes
#define ER 640000     // raw edges
#define ET 660000     // edges incl. self loops
#define D1 128
#define D2 256
#define EPSV 1e-5f
#define SLOPE 0.2f
#define NT1 313       // ceil(NN/64) gemm1 row tiles
#define NHIST 64      // histogram units
#define HCH 10000     // edges per unit; per-node count <= 10000 < 65536 (ushort pack)

typedef __attribute__((ext_vector_type(8))) short bf16x8;
typedef __attribute__((ext_vector_type(4))) float f32x4;

// ---------- helpers ----------
__device__ __forceinline__ int detect64(const void* ei) {
  const int* p = (const int*)ei;
  return (p[1] | p[3] | p[5] | p[7]) == 0;
}
__device__ __forceinline__ int clampn(int v) { return v < 0 ? 0 : (v >= NN ? NN-1 : v); }
__device__ __forceinline__ float bf16_lo(unsigned int u){ return __uint_as_float(u<<16); }
__device__ __forceinline__ float bf16_hi(unsigned int u){ return __uint_as_float(u & 0xffff0000u); }

// ---------- degree histogram: 64 LDS-private ushort-packed units ----------
__global__ void k_hist(const void* ei, unsigned int* dpart, int* gcount) {
  extern __shared__ unsigned int hist[];     // HCH uints = 2 nodes/uint
  int db = blockIdx.x, t = threadIdx.x;
  if (db == 0 && t == 0) *gcount = 0;
  for (int i = t; i < HCH; i += 256) hist[i] = 0;
  __syncthreads();
  int base = db * HCH;
  if (detect64(ei)) {
    const long long* q = (const long long*)ei + ER;
    for (int i = base + t; i < base + HCH; i += 256) {
      int d = clampn((int)q[i]);
      atomicAdd(&hist[d>>1], 1u << ((d&1)*16));
    }
  } else {
    const int* q = (const int*)ei + ER;
    for (int i = base + t; i < base + HCH; i += 256) {
      int d = clampn(q[i]);
      atomicAdd(&hist[d>>1], 1u << ((d&1)*16));
    }
  }
  __syncthreads();
  for (int i = t; i < HCH; i += 256) dpart[(size_t)db*HCH + i] = hist[i];
}

// ---------- parallel segment allocator ----------
__global__ __launch_bounds__(256) void k_alloc(const unsigned int* dpart, int* begv, int* endv,
                                               int* cursor, int* gcount, float* bnz) {
  __shared__ int wsum[4], wbase[4];
  int gid = blockIdx.x*256 + threadIdx.x;
  if (gid < 768) bnz[gid] = 0.f;            // bns1|bnq1|bns2|bnq2
  int d = 0;
  if (gid < NN) {
    d = 1;                                   // self loop
    int half = (gid & 1) * 16;
    int idx = gid >> 1;
    for (int db = 0; db < NHIST; db++)
      d += (dpart[(size_t)db*HCH + idx] >> half) & 0xffff;
  }
  int lane = threadIdx.x & 63, w = threadIdx.x >> 6;
  int v = d;
  #pragma unroll
  for (int o = 1; o < 64; o <<= 1) {
    int u = __shfl_up(v, o);
    if (lane >= o) v += u;
  }
  if (lane == 63) wsum[w] = v;
  __syncthreads();
  if (threadIdx.x == 0) {
    int s0 = wsum[0], s1 = wsum[1], s2 = wsum[2], s3 = wsum[3];
    int b = atomicAdd(gcount, s0 + s1 + s2 + s3);
    wbase[0] = b; wbase[1] = b + s0; wbase[2] = b + s0 + s1; wbase[3] = b + s0 + s1 + s2;
  }
  __syncthreads();
  if (gid < NN) {
    int beg = wbase[w] + v - d;
    begv[gid] = beg; cursor[gid] = beg; endv[gid] = beg + d;
  }
}

// ---------- merged: gemm1 tiles (inline W1 cast) + scatter ----------
__global__ __launch_bounds__(256) void k_gs(const float* x, const float* W1,
                                            const float* att_s1, const float* att_d1,
                                            __hip_bfloat16* hxb, float2* as1, float2* ad1,
                                            const void* ei, int* cursor, int* srcs) {
  __shared__ __hip_bfloat16 As[64][72];
  __shared__ __hip_bfloat16 Bs[128][72];
  __shared__ float asred[4][64], adred[4][64];
  int b = blockIdx.x, t = threadIdx.x;
  if (b >= NT1) {
    // ------- scatter role -------
    int i0 = ((b - NT1)*256 + t)*4;
    if (i0 >= ET) return;
    int s[4], d[4];
    if (i0 >= ER) {
      #pragma unroll
      for (int k = 0; k < 4; k++) { s[k] = i0 + k - ER; d[k] = s[k]; }
    } else if (detect64(ei)) {
      const long long* p64 = (const long long*)ei;
      uint4 qa = *(const uint4*)(p64 + i0);
      uint4 qb = *(const uint4*)(p64 + i0 + 2);
      uint4 ra = *(const uint4*)(p64 + ER + i0);
      uint4 rb = *(const uint4*)(p64 + ER + i0 + 2);
      s[0]=clampn((int)qa.x); s[1]=clampn((int)qa.z); s[2]=clampn((int)qb.x); s[3]=clampn((int)qb.z);
      d[0]=clampn((int)ra.x); d[1]=clampn((int)ra.z); d[2]=clampn((int)rb.x); d[3]=clampn((int)rb.z);
    } else {
      const int* p32 = (const int*)ei;
      uint4 qs = *(const uint4*)(p32 + i0);
      uint4 qd = *(const uint4*)(p32 + ER + i0);
      s[0]=clampn((int)qs.x); s[1]=clampn((int)qs.y); s[2]=clampn((int)qs.z); s[3]=clampn((int)qs.w);
      d[0]=clampn((int)qd.x); d[1]=clampn((int)qd.y); d[2]=clampn((int)qd.z); d[3]=clampn((int)qd.w);
    }
    #pragma unroll
    for (int k = 0; k < 4; k++) {
      int pos = atomicAdd(&cursor[d[k]], 1);
      srcs[pos] = s[k];
    }
    return;
  }
  // ------- gemm1 role -------
  int m0 = b * 64;
  for (int i = t; i < 512; i += 256) {       // stage x fp32->bf16
    int r = i >> 3, s = i & 7;
    int gr = m0 + r; if (gr >= NN) gr = NN - 1;
    float4 f0 = ((const float4*)(x + (size_t)gr*64))[s*2];
    float4 f1 = ((const float4*)(x + (size_t)gr*64))[s*2+1];
    __hip_bfloat16 hb[8] = {
      __float2bfloat16(f0.x), __float2bfloat16(f0.y), __float2bfloat16(f0.z), __float2bfloat16(f0.w),
      __float2bfloat16(f1.x), __float2bfloat16(f1.y), __float2bfloat16(f1.z), __float2bfloat16(f1.w)};
    *(uint4*)&As[r][s*8] = *(uint4*)hb;
  }
  for (int i = t; i < 8192; i += 256) {      // Bs[n][k] = bf16(W1[k][n]) inline transpose-cast
    int n = i & 127, k = i >> 7;
    Bs[n][k] = __float2bfloat16(W1[k*128 + n]);
  }
  __syncthreads();
  int w = t >> 6, lane = t & 63, lm = lane & 15, q = lane >> 4;
  f32x4 acc[4][2];
  #pragma unroll
  for (int rt = 0; rt < 4; rt++)
    #pragma unroll
    for (int ct = 0; ct < 2; ct++) acc[rt][ct] = (f32x4){0.f,0.f,0.f,0.f};
  #pragma unroll
  for (int kc = 0; kc < 2; kc++) {
    bf16x8 bfr[2];
    #pragma unroll
    for (int ct = 0; ct < 2; ct++)
      bfr[ct] = *(const bf16x8*)&Bs[w*32 + ct*16 + lm][kc*32 + q*8];
    #pragma unroll
    for (int rt = 0; rt < 4; rt++) {
      bf16x8 a = *(const bf16x8*)&As[rt*16 + lm][kc*32 + q*8];
      acc[rt][0] = __builtin_amdgcn_mfma_f32_16x16x32_bf16(a, bfr[0], acc[rt][0], 0, 0, 0);
      acc[rt][1] = __builtin_amdgcn_mfma_f32_16x16x32_bf16(a, bfr[1], acc[rt][1], 0, 0, 0);
    }
  }
  #pragma unroll
  for (int rt = 0; rt < 4; rt++)
    #pragma unroll
    for (int ct = 0; ct < 2; ct++)
      #pragma unroll
      for (int rg = 0; rg < 4; rg++) {
        int row = m0 + rt*16 + q*4 + rg;
        int col = w*32 + ct*16 + lm;
        if (row < NN) hxb[(size_t)row*128 + col] = __float2bfloat16(acc[rt][ct][rg]);
      }
  float asc[2], adc[2];
  #pragma unroll
  for (int ct = 0; ct < 2; ct++) {
    int col = w*32 + ct*16 + lm;
    asc[ct] = att_s1[col]; adc[ct] = att_d1[col];
  }
  #pragma unroll
  for (int rt = 0; rt < 4; rt++)
    #pragma unroll
    for (int rg = 0; rg < 4; rg++) {
      float ps = acc[rt][0][rg]*asc[0] + acc[rt][1][rg]*asc[1];
      float pd = acc[rt][0][rg]*adc[0] + acc[rt][1][rg]*adc[1];
      #pragma unroll
      for (int o = 1; o < 16; o <<= 1) { ps += __shfl_xor(ps, o); pd += __shfl_xor(pd, o); }
      if (lm == 0) { int row = rt*16 + q*4 + rg; asred[w][row] = ps; adred[w][row] = pd; }
    }
  __syncthreads();
  if (t < 64) {
    int row = m0 + t;
    if (row < NN) {
      as1[row] = make_float2(asred[0][t] + asred[1][t], asred[2][t] + asred[3][t]);
      ad1[row] = make_float2(adred[0][t] + adred[1][t], adred[2][t] + adred[3][t]);
    }
  }
}

// ---------- MFMA GEMM2: out1 -> BN1+ReLU+cast -> @W2 (inline cast) -> hx2b + att2 ----------
__global__ __launch_bounds__(256) void k_gemm2f(const float* out1, const float* W2,
                                                const float* bns1, const float* bnq1,
                                                const float* gamma1, const float* beta1,
                                                const float* att_s2, const float* att_d2,
                                                __hip_bfloat16* hxb, float2* as2, float2* ad2) {
  __shared__ __hip_bfloat16 As[64][136];
  __shared__ __hip_bfloat16 Bs[256][40];
  __shared__ float AB[2][128];
  __shared__ float asred[4][64], adred[4][64];
  int t = threadIdx.x;
  int m0 = blockIdx.x * 64;
  if (t < 128) {
    float mean = bns1[t]*(1.f/NN);
    float var  = bnq1[t]*(1.f/NN) - mean*mean;
    float A = rsqrtf(var + EPSV)*gamma1[t];
    AB[0][t] = A; AB[1][t] = beta1[t] - mean*A;
  }
  __syncthreads();
  for (int i = t; i < 1024; i += 256) {
    int r = i >> 4, s = i & 15;
    int gr = m0 + r; if (gr >= NN) gr = NN - 1;
    float4 f0 = ((const float4*)(out1 + (size_t)gr*128))[s*2];
    float4 f1 = ((const float4*)(out1 + (size_t)gr*128))[s*2+1];
    int c = s*8;
    float v[8] = {f0.x,f0.y,f0.z,f0.w,f1.x,f1.y,f1.z,f1.w};
    __hip_bfloat16 hb[8];
    #pragma unroll
    for (int k = 0; k < 8; k++)
      hb[k] = __float2bfloat16(fmaxf(v[k]*AB[0][c+k] + AB[1][c+k], 0.f));
    *(uint4*)&As[r][s*8] = *(uint4*)hb;
  }
  int w = t >> 6, lane = t & 63, lm = lane & 15, q = lane >> 4;
  f32x4 acc[4][4];
  #pragma unroll
  for (int rt = 0; rt < 4; rt++)
    #pragma unroll
    for (int ct = 0; ct < 4; ct++) acc[rt][ct] = (f32x4){0.f,0.f,0.f,0.f};
  for (int kc = 0; kc < 4; kc++) {
    __syncthreads();
    for (int i = t; i < 8192; i += 256) {     // Bs[n][kk] = bf16(W2[kc*32+kk][n])
      int n = i & 255, kk = i >> 8;
      Bs[n][kk] = __float2bfloat16(W2[(kc*32 + kk)*256 + n]);
    }
    __syncthreads();
    bf16x8 bfr[4];
    #pragma unroll
    for (int ct = 0; ct < 4; ct++)
      bfr[ct] = *(const bf16x8*)&Bs[w*64 + ct*16 + lm][q*8];
    #pragma unroll
    for (int rt = 0; rt < 4; rt++) {
      bf16x8 a = *(const bf16x8*)&As[rt*16 + lm][kc*32 + q*8];
      #pragma unroll
      for (int ct = 0; ct < 4; ct++)
        acc[rt][ct] = __builtin_amdgcn_mfma_f32_16x16x32_bf16(a, bfr[ct], acc[rt][ct], 0, 0, 0);
    }
  }
  #pragma unroll
  for (int rt = 0; rt < 4; rt++)
    #pragma unroll
    for (int ct = 0; ct < 4; ct++)
      #pragma unroll
      for (int rg = 0; rg < 4; rg++) {
        int row = m0 + rt*16 + q*4 + rg;
        int col = w*64 + ct*16 + lm;
        if (row < NN) hxb[(size_t)row*256 + col] = __float2bfloat16(acc[rt][ct][rg]);
      }
  float asc[4], adc[4];
  #pragma unroll
  for (int ct = 0; ct < 4; ct++) {
    int col = w*64 + ct*16 + lm;
    asc[ct] = att_s2[col]; adc[ct] = att_d2[col];
  }
  #pragma unroll
  for (int rt = 0; rt < 4; rt++)
    #pragma unroll
    for (int rg = 0; rg < 4; rg++) {
      float ps = acc[rt][0][rg]*asc[0] + acc[rt][1][rg]*asc[1]
               + acc[rt][2][rg]*asc[2] + acc[rt][3][rg]*asc[3];
      float pd = acc[rt][0][rg]*adc[0] + acc[rt][1][rg]*adc[1]
               + acc[rt][2][rg]*adc[2] + acc[rt][3][rg]*adc[3];
      #pragma unroll
      for (int o = 1; o < 16; o <<= 1) { ps += __shfl_xor(ps, o); pd += __shfl_xor(pd, o); }
      if (lm == 0) { int row = rt*16 + q*4 + rg; asred[w][row] = ps; adred[w][row] = pd; }
    }
  __syncthreads();
  if (t < 64) {
    int row = m0 + t;
    if (row < NN) {
      as2[row] = make_float2(asred[0][t] + asred[1][t], asred[2][t] + asred[3][t]);
      ad2[row] = make_float2(adred[0][t] + adred[1][t], adred[2][t] + adred[3][t]);
    }
  }
}

// ---------- agg layer1: 64 threads; 16 lanes/edge x uint4, 4 edge slots ----------
__global__ __launch_bounds__(64) void k_agg1(const int* begv, const int* endv, const int* srcs,
                                             const float2* asv, const float2* adv,
                                             const uint4* hx, const float* bias, float* out) {
  __shared__ float2 sp[2][64];
  int n = blockIdx.x, t = threadIdx.x;
  int el = t >> 4, c = t & 15;
  int h = c >> 3;
  float2 ad = adv[n];
  int beg = begv[n], end = endv[n];
  float a[8] = {0.f,0.f,0.f,0.f,0.f,0.f,0.f,0.f};
  float z0 = 0.f, z1 = 0.f;
  for (int cb = beg; cb < end; cb += 64) {
    int len = end - cb; if (len > 64) len = 64;
    if (t < len) {
      int s = srcs[cb + t];
      float2 as = asv[s];
      float e0 = as.x + ad.x, e1 = as.y + ad.y;
      e0 = e0 > 0.f ? e0 : SLOPE*e0;
      e1 = e1 > 0.f ? e1 : SLOPE*e1;
      float p0 = __expf(e0), p1 = __expf(e1);
      sp[0][t] = make_float2(__int_as_float(s), p0);
      sp[1][t] = make_float2(__int_as_float(s), p1);
      z0 += p0; z1 += p1;
    }
    __syncthreads();
    for (int j = 0; j < len; j += 4) {
      int e = j + el;
      if (e < len) {
        float2 v = sp[h][e];
        uint4 u = hx[(size_t)__float_as_int(v.x)*16 + c];
        float pj = v.y;
        a[0] += pj*bf16_lo(u.x); a[1] += pj*bf16_hi(u.x);
        a[2] += pj*bf16_lo(u.y); a[3] += pj*bf16_hi(u.y);
        a[4] += pj*bf16_lo(u.z); a[5] += pj*bf16_hi(u.z);
        a[6] += pj*bf16_lo(u.w); a[7] += pj*bf16_hi(u.w);
      }
    }
    __syncthreads();
  }
  #pragma unroll
  for (int k = 0; k < 8; k++) {
    a[k] += __shfl_down(a[k], 32);
    a[k] += __shfl_down(a[k], 16);
  }
  #pragma unroll
  for (int o = 1; o < 64; o <<= 1) { z0 += __shfl_xor(z0, o); z1 += __shfl_xor(z1, o); }
  if (t < 16) {
    float inv = 1.f / (h ? z1 : z0);
    float4 b0 = ((const float4*)bias)[2*c];
    float4 b1 = ((const float4*)bias)[2*c+1];
    float4 o0 = { a[0]*inv + b0.x, a[1]*inv + b0.y, a[2]*inv + b0.z, a[3]*inv + b0.w };
    float4 o1 = { a[4]*inv + b1.x, a[5]*inv + b1.y, a[6]*inv + b1.z, a[7]*inv + b1.w };
    ((float4*)(out + (size_t)n*D1))[2*c]   = o0;
    ((float4*)(out + (size_t)n*D1))[2*c+1] = o1;
  }
}

// ---------- agg layer2: 64 threads; 32 lanes/edge x uint4, 2 edge slots ----------
__global__ __launch_bounds__(64) void k_agg2(const int* begv, const int* endv, const int* srcs,
                                             const float2* asv, const float2* adv,
                                             const uint4* hx, const float* bias, float* out) {
  __shared__ float2 sp[2][64];
  int n = blockIdx.x, t = threadIdx.x;
  int el = t >> 5, c = t & 31;
  int h = c >> 4;
  float2 ad = adv[n];
  int beg = begv[n], end = endv[n];
  float a[8] = {0.f,0.f,0.f,0.f,0.f,0.f,0.f,0.f};
  float z0 = 0.f, z1 = 0.f;
  for (int cb = beg; cb < end; cb += 64) {
    int len = end - cb; if (len > 64) len = 64;
    if (t < len) {
      int s = srcs[cb + t];
      float2 as = asv[s];
      float e0 = as.x + ad.x, e1 = as.y + ad.y;
      e0 = e0 > 0.f ? e0 : SLOPE*e0;
      e1 = e1 > 0.f ? e1 : SLOPE*e1;
      float p0 = __expf(e0), p1 = __expf(e1);
      sp[0][t] = make_float2(__int_as_float(s), p0);
      sp[1][t] = make_float2(__int_as_float(s), p1);
      z0 += p0; z1 += p1;
    }
    __syncthreads();
    for (int j = 0; j < len; j += 2) {
      int e = j + el;
      if (e < len) {
        float2 v = sp[h][e];
        uint4 u = hx[(size_t)__float_as_int(v.x)*32 + c];
        float pj = v.y;
        a[0] += pj*bf16_lo(u.x); a[1] += pj*bf16_hi(u.x);
        a[2] += pj*bf16_lo(u.y); a[3] += pj*bf16_hi(u.y);
        a[4] += pj*bf16_lo(u.z); a[5] += pj*bf16_hi(u.z);
        a[6] += pj*bf16_lo(u.w); a[7] += pj*bf16_hi(u.w);
      }
    }
    __syncthreads();
  }
  #pragma unroll
  for (int k = 0; k < 8; k++) a[k] += __shfl_down(a[k], 32);
  #pragma unroll
  for (int o = 1; o < 64; o <<= 1) { z0 += __shfl_xor(z0, o); z1 += __shfl_xor(z1, o); }
  if (t < 32) {
    float inv = 1.f / (h ? z1 : z0);
    float4 b0 = ((const float4*)bias)[2*c];
    float4 b1 = ((const float4*)bias)[2*c+1];
    float4 o0 = { a[0]*inv + b0.x, a[1]*inv + b0.y, a[2]*inv + b0.z, a[3]*inv + b0.w };
    float4 o1 = { a[4]*inv + b1.x, a[5]*inv + b1.y, a[6]*inv + b1.z, a[7]*inv + b1.w };
    ((float4*)(out + (size_t)n*D2))[2*c]   = o0;
    ((float4*)(out + (size_t)n*D2))[2*c+1] = o1;
  }
}

// ---------- batchnorm stats ----------
template<int D>
__global__ void k_bnstats(const float* x, float* bnsum, float* bnsq) {
  const int ROWS = 100;
  int c = threadIdx.x;
  int r0 = blockIdx.x * ROWS;
  float s = 0.f, s2 = 0.f;
  for (int r = 0; r < ROWS; r++) {
    float v = x[(size_t)(r0 + r)*D + c];
    s += v; s2 += v*v;
  }
  atomicAdd(&bnsum[c], s);
  atomicAdd(&bnsq[c], s2);
}

// ---------- BN2 apply + ReLU -> fp32 d_out ----------
__global__ void k_bnapply2(const float* x, const float* bnsum, const float* bnsq,
                           const float* gamma, const float* beta, float* out) {
  int i = blockIdx.x*blockDim.x + threadIdx.x;     // float4 index
  if (i >= NN*D2/4) return;
  int c = (i & 63) * 4;
  float4 v = ((const float4*)x)[i];
  float r[4] = {v.x, v.y, v.z, v.w};
  #pragma unroll
  for (int k = 0; k < 4; k++) {
    float mean = bnsum[c+k] * (1.f/NN);
    float var  = bnsq[c+k] * (1.f/NN) - mean*mean;
    float o = (r[k] - mean) * rsqrtf(var + EPSV) * gamma[c+k] + beta[c+k];
    r[k] = o > 0.f ? o : 0.f;
  }
  float4 o4 = {r[0], r[1], r[2], r[3]};
  ((float4*)out)[i] = o4;
}

// ---------- launcher ----------
extern "C" void kernel_launch(void* const* d_in, const int* in_sizes, int n_in,
                              void* d_out, int out_size, void* d_ws, size_t ws_size,
                              hipStream_t stream) {
  const float* x      = (const float*)d_in[0];
  const void*  ei     = d_in[1];
  const float* W1     = (const float*)d_in[2];
  const float* att_s1 = (const float*)d_in[3];
  const float* att_d1 = (const float*)d_in[4];
  const float* bias1  = (const float*)d_in[5];
  const float* gamma1 = (const float*)d_in[6];
  const float* beta1  = (const float*)d_in[7];
  const float* W2     = (const float*)d_in[8];
  const float* att_s2 = (const float*)d_in[9];
  const float* att_d2 = (const float*)d_in[10];
  const float* bias2  = (const float*)d_in[11];
  const float* gamma2 = (const float*)d_in[12];
  const float* beta2  = (const float*)d_in[13];

  char* p = (char*)d_ws;
  __hip_bfloat16* hx1b = (__hip_bfloat16*)p; p += (size_t)NN*D1*2;
  __hip_bfloat16* hx2b = (__hip_bfloat16*)p; p += (size_t)NN*D2*2;
  float* out1 = (float*)p; p += (size_t)NN*D1*4;
  float* out2 = (float*)p; p += (size_t)NN*D2*4;
  float2* as1 = (float2*)p; p += (size_t)NN*8;
  float2* ad1 = (float2*)p; p += (size_t)NN*8;
  float2* as2 = (float2*)p; p += (size_t)NN*8;
  float2* ad2 = (float2*)p; p += (size_t)NN*8;
  float* bns1 = (float*)p; p += D1*4;     // contiguous zero region (768 floats)
  float* bnq1 = (float*)p; p += D1*4;
  float* bns2 = (float*)p; p += D2*4;
  float* bnq2 = (float*)p; p += D2*4;
  unsigned int* dpart = (unsigned int*)p; p += (size_t)NHIST*HCH*4;
  int* begv   = (int*)p; p += NN*4;
  int* endv   = (int*)p; p += NN*4;
  int* cursor = (int*)p; p += NN*4;
  int* gcount = (int*)p; p += 16*4;
  int* srcs   = (int*)p; p += (size_t)ET*4;

  const int SCB = (ET/4 + 255)/256;        // scatter blocks
  k_hist<<<NHIST, 256, HCH*4, stream>>>(ei, dpart, gcount);
  k_alloc<<<(NN+255)/256, 256, 0, stream>>>(dpart, begv, endv, cursor, gcount, bns1);
  k_gs<<<NT1 + SCB, 256, 0, stream>>>(x, W1, att_s1, att_d1, hx1b, as1, ad1,
                                      ei, cursor, srcs);

  k_agg1<<<NN, 64, 0, stream>>>(begv, endv, srcs, as1, ad1, (const uint4*)hx1b, bias1, out1);
  k_bnstats<D1><<<200, D1, 0, stream>>>(out1, bns1, bnq1);

  k_gemm2f<<<(NN+63)/64, 256, 0, stream>>>(out1, W2, bns1, bnq1, gamma1, beta1,
                                           att_s2, att_d2, hx2b, as2, ad2);
  k_agg2<<<NN, 64, 0, stream>>>(begv, endv, srcs, as2, ad2, (const uint4*)hx2b, bias2, out2);
  k_bnstats<D2><<<200, D2, 0, stream>>>(out2, bns2, bnq2);
  k_bnapply2<<<(NN*D2/4 + 255)/256, 256, 0, stream>>>(out2, bns2, bnq2, gamma2, beta2,
                                                      (float*)d_out);
}